// Round 16
// baseline (1377.550 us; speedup 1.0000x reference)
//
#include <hip/hip_runtime.h>
#include <math.h>
#include <stddef.h>

// B=2, H=96, W=192, C=768, NH=12, HD=64, W0=W1=8, S0=S1=4, N=64,
// NW=288 windows/image, B_=576 windows, tokens=36864, HID=3072
#define NTOK   36864
#define CDIM   768
#define HIDDIM 3072
#define QKVDIM 2304

typedef unsigned short u16;
typedef unsigned int   u32;
typedef __attribute__((ext_vector_type(8))) short short8;   // 8 bf16 (4 VGPRs)
typedef __attribute__((ext_vector_type(4))) short short4v;  // 4 bf16
typedef __attribute__((ext_vector_type(4))) float f32x4;

__device__ __forceinline__ float bf2f(u16 h) { return __uint_as_float(((u32)h) << 16); }
__device__ __forceinline__ u16 f2bf(float f) {
  u32 u = __float_as_uint(f);
  u32 r = u + 0x7fffu + ((u >> 16) & 1u);      // RNE
  return (u16)(r >> 16);
}

// window-order row r (0..36863) -> spatial token index (roll -4,-4 + partition)
__device__ __forceinline__ int win_row_to_src(int r) {
  int n = r & 63;
  int wflat = r >> 6;
  int b = wflat / 288;
  int wi = wflat - b * 288;
  int wh = wi / 24;
  int ww = wi - wh * 24;
  int i0 = n >> 3, i1 = n & 7;
  int hh = wh * 8 + i0 + 4; if (hh >= 96)  hh -= 96;
  int wp = ww * 8 + i1 + 4; if (wp >= 192) wp -= 192;
  return b * 18432 + hh * 192 + wp;
}

__device__ __forceinline__ void load_lds16(const u16* g, u16* l) {
  __builtin_amdgcn_global_load_lds((const __attribute__((address_space(1))) void*)g,
                                   (__attribute__((address_space(3))) void*)l, 16, 0, 0);
}

#define SB() __builtin_amdgcn_sched_barrier(0)

// ------- 128x128 bf16 MFMA GEMM: B-direct-from-L2, 4-buffer A, 1 barrier/tile -
// C[M,N] = A[M,K](bf16) @ Wt[N,K](bf16)^T + bias (+RELU) (+bf16 res)
// 8 waves (512 thr), wave (wm,wn)=(wv>>2,wv&3) owns 64x32 out (4 Mf x 2 Nf).
// B (weights, L2-resident under banding) is loaded DIRECTLY into VGPRs
// (double-buffered regs, no LDS) -> no B staging on the barrier path.
// A in LDS with FOUR 16KB buffers (64 KiB; 2 blocks/CU at <=128 regs):
// stage sA(t+3) after the barrier targets buf[(t-1)&3], freed by that barrier.
// Per-iter ledger (issue order pinned): copy B(t)->cur [compiler-waits B(t)];
// issue B(t+1); vmcnt(4) [drains sA(t+2), keeps B(t+1) flying]; s_barrier;
// stage sA(t+3); 8x ds_read A(t); lgkmcnt(0); 16 MFMA. ONE barrier per tile.
// Tail (last 3 iters): vmcnt(0). Swizzle slot^=(row&7) on A both sides (r21).
// Swapped-operand MFMA -> 8B vector stores. m204 XCD map + banded N-halves.
template<int OUTBF, int RELU, int RES>
__launch_bounds__(512, 4)
__global__ void gemm128b(const u16* __restrict__ A, const u16* __restrict__ Wt,
                         const float* __restrict__ bias, const u16* __restrict__ res,
                         void* __restrict__ Cout, int M, int N, int K,
                         int gridx, int nwg)
{
  // bijective XCD chunk map (m204)
  const int orig = blockIdx.x;
  const int xcd  = orig & 7;
  const int q    = nwg >> 3, r8 = nwg & 7;
  const int wgid = (xcd < r8 ? xcd * (q + 1) : r8 * (q + 1) + (xcd - r8) * q) + (orig >> 3);
  int bn, bm;
  if (((gridx | nwg) & 1) == 0) {            // banded decode (B-half per XCD group)
    const int halfn = nwg >> 1, hc = gridx >> 1;
    const int half  = (wgid >= halfn) ? 1 : 0;
    const int w2    = wgid - half * halfn;
    bn = (w2 % hc + half * hc) * 128;
    bm = (w2 / hc) * 128;
  } else {
    bn = (wgid % gridx) * 128;
    bm = (wgid / gridx) * 128;
  }

  __shared__ __align__(16) u16 ldsA[4][128 * 64];   // 4 x 16 KiB A buffers

  const int t    = threadIdx.x;
  const int wv   = t >> 6, lane = t & 63;
  const int wm   = wv >> 2, wn = wv & 3;    // 2M x 4N
  const int lr   = lane & 15, lg = lane >> 4;
  const int sr   = t >> 3;          // staging row within 64-row group (0..63)
  const int ss   = t & 7;           // staging slot (0..7)

  const u16* Abase = A  + (size_t)bm * K;
  const u16* Bbase = Wt + (size_t)bn * K;

  const int nt = K >> 6;            // K-tiles (12 or 48 here)

  // stage A K-tile kt into buffer b: 2 x 16B/lane DMA
  auto stageA = [&](int kt, int b) {
    const int k0 = kt << 6;
#pragma unroll
    for (int j = 0; j < 2; j++) {
      int row  = j * 64 + sr;
      int slot = ss ^ (row & 7);
      load_lds16(Abase + (size_t)row * K + k0 + slot * 8, &ldsA[b][j * 4096 + t * 8]);
    }
  };
  // load B fragments for K-tile kt directly from global into regs (4 x b128)
  auto loadB = [&](int kt, short8 bf[2][2]) {
    const int k0 = kt << 6;
#pragma unroll
    for (int nf = 0; nf < 2; nf++)
#pragma unroll
      for (int ks = 0; ks < 2; ks++) {
        int row = wn * 32 + nf * 16 + lr;
        bf[nf][ks] = *(const short8*)(Bbase + (size_t)row * K + k0 + ks * 32 + lg * 8);
      }
  };

  f32x4 acc[4][2] = {};
  short8 bcur[2][2], bnxt[2][2];

  // prologue: A tiles 0,1,2 in flight; B(0) in flight
  stageA(0, 0); stageA(1, 1); stageA(2, 2);
  loadB(0, bnxt);

  for (int tt = 0; tt < nt; tt++) {
    // 1) promote B(tt) to cur (compiler inserts the wait for its loads)
#pragma unroll
    for (int nf = 0; nf < 2; nf++)
#pragma unroll
      for (int ks = 0; ks < 2; ks++)
        bcur[nf][ks] = bnxt[nf][ks];
    SB();
    // 2) prefetch B(tt+1)
    if (tt + 1 < nt) loadB(tt + 1, bnxt);
    SB();
    // 3) counted drain: sA(tt+2) done, B(tt+1) stays in flight
    if (tt < nt - 3) asm volatile("s_waitcnt vmcnt(4)" ::: "memory");
    else             asm volatile("s_waitcnt vmcnt(0)" ::: "memory");
    SB();
    // 4) the ONE barrier: frees buf[(tt-1)&3] and publishes buf[tt&3]
    __builtin_amdgcn_s_barrier();
    SB();
    // 5) stage A(tt+3) into the just-freed buffer
    if (tt + 3 < nt) stageA(tt + 3, (tt + 3) & 3);
    SB();
    // 6) read A fragments from buf[tt&3]
    const u16* Ab = &ldsA[tt & 3][0];
    short8 afr[4][2];
#pragma unroll
    for (int mf = 0; mf < 4; mf++)
#pragma unroll
      for (int ks = 0; ks < 2; ks++) {
        int row = wm * 64 + mf * 16 + lr;
        afr[mf][ks] = *(const short8*)(Ab + row * 64 + (((ks * 4 + lg) ^ (row & 7)) << 3));
      }
    asm volatile("s_waitcnt lgkmcnt(0)" ::: "memory");
    __builtin_amdgcn_sched_barrier(0);
    // 7) 16 MFMA (swapped operands: C[reg]=n, C[lane]=m)
    __builtin_amdgcn_s_setprio(1);
#pragma unroll
    for (int ks = 0; ks < 2; ks++)
#pragma unroll
      for (int mf = 0; mf < 4; mf++)
#pragma unroll
        for (int nf = 0; nf < 2; nf++)
          acc[mf][nf] = __builtin_amdgcn_mfma_f32_16x16x32_bf16(bcur[nf][ks], afr[mf][ks], acc[mf][nf], 0, 0, 0);
    __builtin_amdgcn_s_setprio(0);
  }

  // swapped C/D: per lane row m = lr, cols n = lg*4 + j (4 consecutive)
#pragma unroll
  for (int mf = 0; mf < 4; mf++) {
    size_t row = (size_t)(bm + wm * 64 + mf * 16 + lr);
#pragma unroll
    for (int nf = 0; nf < 2; nf++) {
      int col0 = bn + wn * 32 + nf * 16 + lg * 4;
      float4 b4 = *(const float4*)(bias + col0);
      float v0 = acc[mf][nf][0] + b4.x;
      float v1 = acc[mf][nf][1] + b4.y;
      float v2 = acc[mf][nf][2] + b4.z;
      float v3 = acc[mf][nf][3] + b4.w;
      if (RELU) {
        v0 = fmaxf(v0, 0.f); v1 = fmaxf(v1, 0.f);
        v2 = fmaxf(v2, 0.f); v3 = fmaxf(v3, 0.f);
      }
      if (RES) {
        short4v rv = *(const short4v*)(res + row * N + col0);
        v0 += bf2f((u16)rv[0]); v1 += bf2f((u16)rv[1]);
        v2 += bf2f((u16)rv[2]); v3 += bf2f((u16)rv[3]);
      }
      if (OUTBF) {
        short4v o;
        o[0] = (short)f2bf(v0); o[1] = (short)f2bf(v1);
        o[2] = (short)f2bf(v2); o[3] = (short)f2bf(v3);
        *(short4v*)((u16*)Cout + row * N + col0) = o;
      } else {
        f32x4 o = {v0, v1, v2, v3};
        *(f32x4*)((float*)Cout + row * N + col0) = o;
      }
    }
  }
}

// ---------------- conversions ----------------
// wave-per-row gather: 4 rows/block, float4 in, bf16x4 out
__launch_bounds__(256)
__global__ void gather_x_bf16(const float* __restrict__ x, u16* __restrict__ xg)
{
  const int t = threadIdx.x, wv = t >> 6, lane = t & 63;
  const int r = blockIdx.x * 4 + wv;
  const float4* src = (const float4*)(x + (size_t)win_row_to_src(r) * CDIM);
  short4v* dst = (short4v*)(xg + (size_t)r * CDIM);
#pragma unroll
  for (int e = 0; e < 3; e++) {
    float4 f = src[e * 64 + lane];
    short4v o;
    o[0] = (short)f2bf(f.x); o[1] = (short)f2bf(f.y);
    o[2] = (short)f2bf(f.z); o[3] = (short)f2bf(f.w);
    dst[e * 64 + lane] = o;
  }
}

// merged 4-weight fp32->bf16 conversion (outputs contiguous in ws)
// sizes: w_qkv 1769472 | w_proj 589824 | w_fc1 2359296 | w_fc2 2359296
__launch_bounds__(256)
__global__ void conv4_bf16(const float* __restrict__ s0, const float* __restrict__ s1,
                           const float* __restrict__ s2, const float* __restrict__ s3,
                           u16* __restrict__ out)
{
  const int i = blockIdx.x * 256 + threadIdx.x;   // float4 index, 1769472 total
  const int e = i * 4;
  const float* src; int off;
  if (e < 1769472)      { src = s0; off = 0; }
  else if (e < 2359296) { src = s1; off = 1769472; }
  else if (e < 4718592) { src = s2; off = 2359296; }
  else                  { src = s3; off = 4718592; }
  float4 f = *(const float4*)(src + (e - off));
  short4v o;
  o[0] = (short)f2bf(f.x); o[1] = (short)f2bf(f.y);
  o[2] = (short)f2bf(f.z); o[3] = (short)f2bf(f.w);
  *(short4v*)(out + e) = o;
}

// ---------------- MFMA attention (one wave per window-head) ----------------
__launch_bounds__(256)
__global__ void attn_mfma(const u16* __restrict__ qkv, const float* __restrict__ mask,
                          u16* __restrict__ out)
{
  __shared__ u16 vt[4][4096];        // V^T per wave: [d][m]
  __shared__ u16 pbuf[4][4096];      // P per wave: [n][m]
  __shared__ float ropetab[512];     // (cos,sin) for (p in 0..31, pos in 0..7)

  const int t = threadIdx.x;
  {
    int p = t >> 3, pos = t & 7;
    float inv = __expf(-(float)(p & 15) * 0.5756462732485115f);  // 10000^(-(p&15)/16)
    float sv, cv;
    sincosf((float)pos * inv, &sv, &cv);
    ropetab[t * 2]     = cv;
    ropetab[t * 2 + 1] = sv;
  }
  __syncthreads();

  const int wv = t >> 6, lane = t & 63;
  const int lr = lane & 15, lg = lane >> 4;
  const int gp   = blockIdx.x * 4 + wv;
  const int head = gp % 12;
  const int lw   = gp / 12;          // global window 0..575
  const int widx = lw % 288;
  const u16* base = qkv + (size_t)lw * 64 * QKVDIM + head * 64;

  // --- stage V^T: lane reads V row m=lane (64 d), scatters to vt[d][m] ---
  {
    const u16* vrow = base + 1536 + (size_t)lane * QKVDIM;
    u16* vb = vt[wv];
#pragma unroll
    for (int s = 0; s < 8; s++) {
      short8 v = *(const short8*)(vrow + s * 8);
#pragma unroll
      for (int j = 0; j < 8; j++) {
        int d = s * 8 + j;
        vb[d * 64 + ((((lane >> 3) ^ (d & 7)) << 3) | (lane & 7))] = (u16)v[j];
      }
    }
  }

  // --- load Q,K fragments with RoPE ---
  short8 aq[4][2], ak[4][2];
#pragma unroll
  for (int f = 0; f < 4; f++) {
#pragma unroll
    for (int ks = 0; ks < 2; ks++) {
      int n = f * 16 + lr;
      short8 qv = *(const short8*)(base + (size_t)n * QKVDIM + ks * 32 + lg * 8);
      short8 kv = *(const short8*)(base + (size_t)n * QKVDIM + 768 + ks * 32 + lg * 8);
      short8 qo, ko;
#pragma unroll
      for (int jj = 0; jj < 4; jj++) {
        int p   = ks * 16 + lg * 4 + jj;
        int pos = (p < 16) ? (n >> 3) : (n & 7);
        float cv = ropetab[(p * 8 + pos) * 2];
        float sv = ropetab[(p * 8 + pos) * 2 + 1];
        float q1 = bf2f((u16)qv[2 * jj]), q2 = bf2f((u16)qv[2 * jj + 1]);
        float k1 = bf2f((u16)kv[2 * jj]), k2 = bf2f((u16)kv[2 * jj + 1]);
        qo[2 * jj]     = (short)f2bf((q1 * cv - q2 * sv) * 0.125f);
        qo[2 * jj + 1] = (short)f2bf((q1 * sv + q2 * cv) * 0.125f);
        ko[2 * jj]     = (short)f2bf(k1 * cv - k2 * sv);
        ko[2 * jj + 1] = (short)f2bf(k1 * sv + k2 * cv);
      }
      aq[f][ks] = qo; ak[f][ks] = ko;
    }
  }

  // --- S = Q K^T ---
  f32x4 sf[4][4] = {};
#pragma unroll
  for (int ks = 0; ks < 2; ks++)
#pragma unroll
    for (int fn = 0; fn < 4; fn++)
#pragma unroll
      for (int fm = 0; fm < 4; fm++)
        sf[fn][fm] = __builtin_amdgcn_mfma_f32_16x16x32_bf16(aq[fn][ks], ak[fm][ks], sf[fn][fm], 0, 0, 0);

  // --- + mask ---
  const float* mrow = mask + (size_t)widx * 4096;
#pragma unroll
  for (int fn = 0; fn < 4; fn++)
#pragma unroll
    for (int fm = 0; fm < 4; fm++)
#pragma unroll
      for (int j = 0; j < 4; j++)
        sf[fn][fm][j] += mrow[(fn * 16 + lg * 4 + j) * 64 + fm * 16 + lr];

  // --- softmax over m ---
#pragma unroll
  for (int fn = 0; fn < 4; fn++) {
#pragma unroll
    for (int j = 0; j < 4; j++) {
      float m0 = fmaxf(fmaxf(sf[fn][0][j], sf[fn][1][j]),
                       fmaxf(sf[fn][2][j], sf[fn][3][j]));
      m0 = fmaxf(m0, __shfl_xor(m0, 1));
      m0 = fmaxf(m0, __shfl_xor(m0, 2));
      m0 = fmaxf(m0, __shfl_xor(m0, 4));
      m0 = fmaxf(m0, __shfl_xor(m0, 8));
      float s0 = 0.f;
#pragma unroll
      for (int fm = 0; fm < 4; fm++) {
        float e = __expf(sf[fn][fm][j] - m0);
        sf[fn][fm][j] = e;
        s0 += e;
      }
      s0 += __shfl_xor(s0, 1);
      s0 += __shfl_xor(s0, 2);
      s0 += __shfl_xor(s0, 4);
      s0 += __shfl_xor(s0, 8);
      float r = 1.f / s0;
#pragma unroll
      for (int fm = 0; fm < 4; fm++) sf[fn][fm][j] *= r;
    }
  }

  // --- write P[n][m] bf16 to LDS (swizzled slots) ---
  u16* pb = pbuf[wv];
#pragma unroll
  for (int fn = 0; fn < 4; fn++)
#pragma unroll
    for (int fm = 0; fm < 4; fm++)
#pragma unroll
      for (int j = 0; j < 4; j++) {
        int n = fn * 16 + lg * 4 + j, m = fm * 16 + lr;
        pb[n * 64 + ((((m >> 3) ^ (n & 7)) << 3) | (m & 7))] = f2bf(sf[fn][fm][j]);
      }
  asm volatile("s_waitcnt lgkmcnt(0)" ::: "memory");   // wave-local LDS drain
  __builtin_amdgcn_sched_barrier(0);

  // --- O = P V, swapped: o = mfma(V^T-frag, P-frag) -> C[d(reg)][n(lane)] ---
  short8 ap[4][2], bvf[4][2];
#pragma unroll
  for (int f = 0; f < 4; f++)
#pragma unroll
    for (int ks = 0; ks < 2; ks++) {
      int rn = f * 16 + lr;
      ap[f][ks]  = *(const short8*)(pb     + rn * 64 + (((ks * 4 + lg) ^ (rn & 7)) << 3));
      bvf[f][ks] = *(const short8*)(vt[wv] + rn * 64 + (((ks * 4 + lg) ^ (rn & 7)) << 3));
    }
  f32x4 o[4][4] = {};
#pragma unroll
  for (int ks = 0; ks < 2; ks++)
#pragma unroll
    for (int fn = 0; fn < 4; fn++)
#pragma unroll
      for (int fd = 0; fd < 4; fd++)
        o[fn][fd] = __builtin_amdgcn_mfma_f32_16x16x32_bf16(bvf[fd][ks], ap[fn][ks], o[fn][fd], 0, 0, 0);

  // per lane: row n = fn*16 + lr, cols d = fd*16 + lg*4 + j -> 8B stores
  u16* ob = out + ((size_t)lw * 64) * CDIM + head * 64;
#pragma unroll
  for (int fn = 0; fn < 4; fn++) {
    size_t nrow = (size_t)(fn * 16 + lr) * CDIM;
#pragma unroll
    for (int fd = 0; fd < 4; fd++) {
      int d0 = fd * 16 + lg * 4;
      short4v ov;
      ov[0] = (short)f2bf(o[fn][fd][0]);
      ov[1] = (short)f2bf(o[fn][fd][1]);
      ov[2] = (short)f2bf(o[fn][fd][2]);
      ov[3] = (short)f2bf(o[fn][fd][3]);
      *(short4v*)(ob + nrow + d0) = ov;
    }
  }
}

// ---------------- LayerNorms (wave-per-token, shfl reduction) ----------------
// LN1: in = xg[r](bf16) + proj[r](bf16), r = win_row(tok); out x1[tok] bf16.
__launch_bounds__(256)
__global__ void ln1_kernel(const u16* __restrict__ xg, const u16* __restrict__ add,
                           const float* __restrict__ g, const float* __restrict__ bb,
                           u16* __restrict__ out)
{
  const int t = threadIdx.x, wv = t >> 6, lane = t & 63;
  const int tok = blockIdx.x * 4 + wv;
  int b = tok / 18432;
  int hw = tok - b * 18432;
  int h = hw / 192, w = hw - h * 192;
  int h2 = h - 4; if (h2 < 0) h2 += 96;
  int w2 = w - 4; if (w2 < 0) w2 += 192;
  int r = ((b * 12 + (h2 >> 3)) * 24 + (w2 >> 3)) * 64 + (h2 & 7) * 8 + (w2 & 7);
  const short4v* a0 = (const short4v*)(xg  + (size_t)r * CDIM);
  const short4v* a1 = (const short4v*)(add + (size_t)r * CDIM);

  float v[12];
  float s1 = 0.f, s2 = 0.f;
#pragma unroll
  for (int e = 0; e < 3; e++) {
    short4v f = a0[e * 64 + lane];
    short4v a = a1[e * 64 + lane];
#pragma unroll
    for (int j = 0; j < 4; j++) {
      float x = bf2f((u16)f[j]) + bf2f((u16)a[j]);
      v[e*4+j] = x; s1 += x; s2 += x * x;
    }
  }
#pragma unroll
  for (int m = 1; m < 64; m <<= 1) {
    s1 += __shfl_xor(s1, m);
    s2 += __shfl_xor(s2, m);
  }
  float mean = s1 * (1.f / 768.f);
  float var  = s2 * (1.f / 768.f) - mean * mean;
  float rs   = rsqrtf(var + 1e-5f);
  short4v* dst = (short4v*)(out + (size_t)tok * CDIM);
#pragma unroll
  for (int e = 0; e < 3; e++) {
    short4v o;
#pragma unroll
    for (int j = 0; j < 4; j++) {
      int c = (e * 64 + lane) * 4 + j;
      o[j] = (short)f2bf((v[e*4+j] - mean) * rs * g[c] + bb[c]);
    }
    dst[e * 64 + lane] = o;
  }
}

// LN2: in bf16 (short4), out fp32 (float4)
__launch_bounds__(256)
__global__ void ln2_kernel(const u16* __restrict__ xin, const float* __restrict__ g,
                           const float* __restrict__ bb, float* __restrict__ out)
{
  const int t = threadIdx.x, wv = t >> 6, lane = t & 63;
  const int tok = blockIdx.x * 4 + wv;
  const short4v* a0 = (const short4v*)(xin + (size_t)tok * CDIM);

  float v[12];
  float s1 = 0.f, s2 = 0.f;
#pragma unroll
  for (int e = 0; e < 3; e++) {
    short4v a = a0[e * 64 + lane];
#pragma unroll
    for (int j = 0; j < 4; j++) {
      float x = bf2f((u16)a[j]);
      v[e*4+j] = x; s1 += x; s2 += x * x;
    }
  }
#pragma unroll
  for (int m = 1; m < 64; m <<= 1) {
    s1 += __shfl_xor(s1, m);
    s2 += __shfl_xor(s2, m);
  }
  float mean = s1 * (1.f / 768.f);
  float var  = s2 * (1.f / 768.f) - mean * mean;
  float rs   = rsqrtf(var + 1e-5f);
  float4* dst = (float4*)(out + (size_t)tok * CDIM);
#pragma unroll
  for (int e = 0; e < 3; e++) {
    float4 o;
    int c = (e * 64 + lane) * 4;
    o.x = (v[e*4+0] - mean) * rs * g[c+0] + bb[c+0];
    o.y = (v[e*4+1] - mean) * rs * g[c+1] + bb[c+1];
    o.z = (v[e*4+2] - mean) * rs * g[c+2] + bb[c+2];
    o.w = (v[e*4+3] - mean) * rs * g[c+3] + bb[c+3];
    dst[e * 64 + lane] = o;
  }
}

static inline void launch_gemm(const u16* A, const u16* Wt, const float* bias,
                               const u16* res, void* C, int M, int N, int K,
                               int outbf, int relu, int resf, hipStream_t s)
{
  int gridx = N / 128, nwg = gridx * (M / 128);
  if (outbf) {
    if (relu)      gemm128b<1,1,0><<<nwg, 512, 0, s>>>(A, Wt, bias, res, C, M, N, K, gridx, nwg);
    else if (resf) gemm128b<1,0,1><<<nwg, 512, 0, s>>>(A, Wt, bias, res, C, M, N, K, gridx, nwg);
    else           gemm128b<1,0,0><<<nwg, 512, 0, s>>>(A, Wt, bias, res, C, M, N, K, gridx, nwg);
  } else {
    gemm128b<0,0,0><<<nwg, 512, 0, s>>>(A, Wt, bias, res, C, M, N, K, gridx, nwg);
  }
}

extern "C" void kernel_launch(void* const* d_in, const int* in_sizes, int n_in,
                              void* d_out, int out_size, void* d_ws, size_t ws_size,
                              hipStream_t stream)
{
  const float* x      = (const float*)d_in[0];
  const float* mask   = (const float*)d_in[1];
  const float* w_qkv  = (const float*)d_in[2];
  const float* b_qkv  = (const float*)d_in[3];
  const float* w_proj = (const float*)d_in[4];
  const float* b_proj = (const float*)d_in[5];
  const float* g1     = (const float*)d_in[6];
  const float* b1     = (const float*)d_in[7];
  const float* g2     = (const float*)d_in[8];
  const float* b2     = (const float*)d_in[9];
  const float* w_fc1  = (const float*)d_in[10];
  const float* b_fc1  = (const float*)d_in[11];
  const float* w_fc2  = (const float*)d_in[12];
  const float* b_fc2  = (const float*)d_in[13];
  float* out = (float*)d_out;

  // ws layout, total 297,271,296 B:
  //  A0 [0, 56.6M):        xg -> h[0:56.6M)
  //  A1 [56.6M, 226.5M):   QKV -> proj-out -> h[56.6M:226.5M)
  //  A2 [226.5M, 283.1M):  AO -> x1 -> y (in-place)
  //  W  [283.1M, 297.3M):  bf16 weights (contiguous: qkv|proj|fc1|fc2)
  char* base = (char*)d_ws;
  u16* A0 = (u16*)base;
  u16* A1 = (u16*)(base + 56623104);
  u16* A2 = (u16*)(base + 226492416);
  u16* Hb = (u16*)base;
  u16* wqkvb  = (u16*)(base + 283115520);
  u16* wprojb = wqkvb  + 1769472;
  u16* wfc1b  = wprojb + 589824;
  u16* wfc2b  = wfc1b  + 2359296;

  // all 4 weight conversions in ONE dispatch (outputs contiguous at wqkvb)
  conv4_bf16<<<1769472 / 256, 256, 0, stream>>>(w_qkv, w_proj, w_fc1, w_fc2, wqkvb);
  gather_x_bf16<<<NTOK / 4, 256, 0, stream>>>(x, A0);

  // QKV (full) then attention (all 576 windows) -> AO in A2
  launch_gemm(A0, wqkvb, b_qkv, nullptr, A1, NTOK, QKVDIM, CDIM, 1, 0, 0, stream);
  attn_mfma<<<576 * 12 / 4, 256, 0, stream>>>(A1, mask, A2);

  // proj: AO(A2) -> proj-out (A1, QKV dead)
  launch_gemm(A2, wprojb, b_proj, nullptr, A1, NTOK, CDIM, CDIM, 1, 0, 0, stream);

  // LN1: xg(A0) + proj-out(A1), both at row r -> x1 into A2 (AO dead)
  ln1_kernel<<<NTOK / 4, 256, 0, stream>>>(A0, A1, g1, b1, A2);

  // MLP, single dispatches: h full into A0+A1 (xg/proj dead); y in-place over x1
  launch_gemm(A2, wfc1b, b_fc1, nullptr, Hb, NTOK, HIDDIM, CDIM, 1, 1, 0, stream);
  launch_gemm(Hb, wfc2b, b_fc2, A2, A2, NTOK, CDIM, HIDDIM, 1, 0, 1, stream);

  // LN2 -> out (fp32)
  ln2_kernel<<<NTOK / 4, 256, 0, stream>>>(A2, g2, b2, out);
}

// Round 17
// 915.560 us; speedup vs baseline: 1.5046x; 1.5046x over previous
//
#include <hip/hip_runtime.h>
#include <math.h>
#include <stddef.h>

// B=2, H=96, W=192, C=768, NH=12, HD=64, W0=W1=8, S0=S1=4, N=64,
// NW=288 windows/image, B_=576 windows, tokens=36864, HID=3072
#define NTOK   36864
#define CDIM   768
#define HIDDIM 3072
#define QKVDIM 2304

typedef unsigned short u16;
typedef unsigned int   u32;
typedef __attribute__((ext_vector_type(8))) short short8;   // 8 bf16 (4 VGPRs)
typedef __attribute__((ext_vector_type(4))) short short4v;  // 4 bf16
typedef __attribute__((ext_vector_type(4))) float f32x4;
typedef __attribute__((ext_vector_type(16))) float f32x16;

__device__ __forceinline__ float bf2f(u16 h) { return __uint_as_float(((u32)h) << 16); }
__device__ __forceinline__ u16 f2bf(float f) {
  u32 u = __float_as_uint(f);
  u32 r = u + 0x7fffu + ((u >> 16) & 1u);      // RNE
  return (u16)(r >> 16);
}

// window-order row r (0..36863) -> spatial token index (roll -4,-4 + partition)
__device__ __forceinline__ int win_row_to_src(int r) {
  int n = r & 63;
  int wflat = r >> 6;
  int b = wflat / 288;
  int wi = wflat - b * 288;
  int wh = wi / 24;
  int ww = wi - wh * 24;
  int i0 = n >> 3, i1 = n & 7;
  int hh = wh * 8 + i0 + 4; if (hh >= 96)  hh -= 96;
  int wp = ww * 8 + i1 + 4; if (wp >= 192) wp -= 192;
  return b * 18432 + hh * 192 + wp;
}

__device__ __forceinline__ void load_lds16(const u16* g, u16* l) {
  __builtin_amdgcn_global_load_lds((const __attribute__((address_space(1))) void*)g,
                                   (__attribute__((address_space(3))) void*)l, 16, 0, 0);
}

// ---------------- 128x128 bf16 MFMA GEMM, 8 waves, 2 blocks/CU (r15) ---------
// 16x16x32 fragments. Measured best baseline: 0 conflicts, MfmaUtil 33.7%.
template<int OUTBF, int RELU, int RES>
__launch_bounds__(512, 4)
__global__ void gemm128(const u16* __restrict__ A, const u16* __restrict__ Wt,
                        const float* __restrict__ bias, const u16* __restrict__ res,
                        void* __restrict__ Cout, int M, int N, int K,
                        int gridx, int nwg)
{
  const int orig = blockIdx.x;
  const int xcd  = orig & 7;
  const int q    = nwg >> 3, r8 = nwg & 7;
  const int wgid = (xcd < r8 ? xcd * (q + 1) : r8 * (q + 1) + (xcd - r8) * q) + (orig >> 3);
  int bn, bm;
  if (((gridx | nwg) & 1) == 0) {
    const int halfn = nwg >> 1, hc = gridx >> 1;
    const int half  = (wgid >= halfn) ? 1 : 0;
    const int w2    = wgid - half * halfn;
    bn = (w2 % hc + half * hc) * 128;
    bm = (w2 / hc) * 128;
  } else {
    bn = (wgid % gridx) * 128;
    bm = (wgid / gridx) * 128;
  }

  __shared__ __align__(16) u16 lds[2][2][128 * 64];

  const int t    = threadIdx.x;
  const int wv   = t >> 6, lane = t & 63;
  const int wm   = wv >> 2, wn = wv & 3;
  const int lr   = lane & 15, lg = lane >> 4;
  const int sr   = t >> 3;
  const int ss   = t & 7;

  const u16* Abase = A  + (size_t)bm * K;
  const u16* Bbase = Wt + (size_t)bn * K;

  const int nt = K >> 6;

  auto stage = [&](int kt, int b) {
    const int k0 = kt << 6;
#pragma unroll
    for (int j = 0; j < 2; j++) {
      int row  = j * 64 + sr;
      int slot = ss ^ (row & 7);
      load_lds16(Abase + (size_t)row * K + k0 + slot * 8, &lds[b][0][j * 4096 + t * 8]);
    }
#pragma unroll
    for (int j = 0; j < 2; j++) {
      int row  = j * 64 + sr;
      int slot = ss ^ (row & 7);
      load_lds16(Bbase + (size_t)row * K + k0 + slot * 8, &lds[b][1][j * 4096 + t * 8]);
    }
  };

  f32x4 acc[4][2] = {};

  stage(0, 0);
  stage(1, 1);

  for (int tt = 0; tt < nt; tt++) {
    const int cur = tt & 1;
    if (tt + 1 < nt) asm volatile("s_waitcnt vmcnt(4)" ::: "memory");
    else             asm volatile("s_waitcnt vmcnt(0)" ::: "memory");
    __builtin_amdgcn_s_barrier();

    const u16* Ab = &lds[cur][0][0];
    const u16* Bb = &lds[cur][1][0];

    short8 bfr[2][2], afr[2][2];
#pragma unroll
    for (int nf = 0; nf < 2; nf++)
#pragma unroll
      for (int ks = 0; ks < 2; ks++) {
        int row = wn * 32 + nf * 16 + lr;
        bfr[nf][ks] = *(const short8*)(Bb + row * 64 + (((ks * 4 + lg) ^ (row & 7)) << 3));
      }
#pragma unroll
    for (int mf = 0; mf < 2; mf++)
#pragma unroll
      for (int ks = 0; ks < 2; ks++) {
        int row = wm * 64 + mf * 16 + lr;
        afr[mf][ks] = *(const short8*)(Ab + row * 64 + (((ks * 4 + lg) ^ (row & 7)) << 3));
      }
    asm volatile("s_waitcnt lgkmcnt(0)" ::: "memory");
    __builtin_amdgcn_sched_barrier(0);
    __builtin_amdgcn_s_setprio(1);
#pragma unroll
    for (int ks = 0; ks < 2; ks++)
#pragma unroll
      for (int mf = 0; mf < 2; mf++)
#pragma unroll
        for (int nf = 0; nf < 2; nf++)
          acc[mf][nf] = __builtin_amdgcn_mfma_f32_16x16x32_bf16(bfr[nf][ks], afr[mf][ks], acc[mf][nf], 0, 0, 0);
    __builtin_amdgcn_s_setprio(0);

    short8 afr2[2][2];
#pragma unroll
    for (int mf = 0; mf < 2; mf++)
#pragma unroll
      for (int ks = 0; ks < 2; ks++) {
        int row = wm * 64 + (mf + 2) * 16 + lr;
        afr2[mf][ks] = *(const short8*)(Ab + row * 64 + (((ks * 4 + lg) ^ (row & 7)) << 3));
      }
    asm volatile("s_waitcnt lgkmcnt(0)" ::: "memory");
    __builtin_amdgcn_sched_barrier(0);
    __builtin_amdgcn_s_barrier();

    if (tt + 2 < nt) stage(tt + 2, cur);

    __builtin_amdgcn_s_setprio(1);
#pragma unroll
    for (int ks = 0; ks < 2; ks++)
#pragma unroll
      for (int mf = 0; mf < 2; mf++)
#pragma unroll
        for (int nf = 0; nf < 2; nf++)
          acc[mf + 2][nf] = __builtin_amdgcn_mfma_f32_16x16x32_bf16(bfr[nf][ks], afr2[mf][ks], acc[mf + 2][nf], 0, 0, 0);
    __builtin_amdgcn_s_setprio(0);
  }

#pragma unroll
  for (int mf = 0; mf < 4; mf++) {
    size_t row = (size_t)(bm + wm * 64 + mf * 16 + lr);
#pragma unroll
    for (int nf = 0; nf < 2; nf++) {
      int col0 = bn + wn * 32 + nf * 16 + lg * 4;
      float4 b4 = *(const float4*)(bias + col0);
      float v0 = acc[mf][nf][0] + b4.x;
      float v1 = acc[mf][nf][1] + b4.y;
      float v2 = acc[mf][nf][2] + b4.z;
      float v3 = acc[mf][nf][3] + b4.w;
      if (RELU) {
        v0 = fmaxf(v0, 0.f); v1 = fmaxf(v1, 0.f);
        v2 = fmaxf(v2, 0.f); v3 = fmaxf(v3, 0.f);
      }
      if (RES) {
        short4v rv = *(const short4v*)(res + row * N + col0);
        v0 += bf2f((u16)rv[0]); v1 += bf2f((u16)rv[1]);
        v2 += bf2f((u16)rv[2]); v3 += bf2f((u16)rv[3]);
      }
      if (OUTBF) {
        short4v o;
        o[0] = (short)f2bf(v0); o[1] = (short)f2bf(v1);
        o[2] = (short)f2bf(v2); o[3] = (short)f2bf(v3);
        *(short4v*)((u16*)Cout + row * N + col0) = o;
      } else {
        f32x4 o = {v0, v1, v2, v3};
        *(f32x4*)((float*)Cout + row * N + col0) = o;
      }
    }
  }
}

// ------- 128x128 bf16 GEMM, 32x32x16 MFMA variant (FC experiment) -----------
// Same skeleton/LDS/staging/swizzle as gemm128; wave tile 64x32 = 2 M-frags of
// 32x32. Per K-tile: 8 MFMA (vs 16), each 2x FLOP at the higher 2382 TF
// ceiling. A/B in-layout: row = lane&31, k = (lane>>5)*8 + j. Swapped operands
// -> C: n = (reg&3) + 8*(reg>>2) + 4*(lane>>5) (4-consecutive groups), m =
// lane&31 -> same 8B vector-store epilogue.
template<int OUTBF, int RELU, int RES>
__launch_bounds__(512, 4)
__global__ void gemm128w(const u16* __restrict__ A, const u16* __restrict__ Wt,
                         const float* __restrict__ bias, const u16* __restrict__ res,
                         void* __restrict__ Cout, int M, int N, int K,
                         int gridx, int nwg)
{
  const int orig = blockIdx.x;
  const int xcd  = orig & 7;
  const int q    = nwg >> 3, r8 = nwg & 7;
  const int wgid = (xcd < r8 ? xcd * (q + 1) : r8 * (q + 1) + (xcd - r8) * q) + (orig >> 3);
  int bn, bm;
  if (((gridx | nwg) & 1) == 0) {
    const int halfn = nwg >> 1, hc = gridx >> 1;
    const int half  = (wgid >= halfn) ? 1 : 0;
    const int w2    = wgid - half * halfn;
    bn = (w2 % hc + half * hc) * 128;
    bm = (w2 / hc) * 128;
  } else {
    bn = (wgid % gridx) * 128;
    bm = (wgid / gridx) * 128;
  }

  __shared__ __align__(16) u16 lds[2][2][128 * 64];

  const int t    = threadIdx.x;
  const int wv   = t >> 6, lane = t & 63;
  const int wm   = wv >> 2, wn = wv & 3;    // 2M x 4N
  const int l31  = lane & 31, hi = lane >> 5;
  const int sr   = t >> 3;
  const int ss   = t & 7;

  const u16* Abase = A  + (size_t)bm * K;
  const u16* Bbase = Wt + (size_t)bn * K;

  const int nt = K >> 6;

  auto stage = [&](int kt, int b) {
    const int k0 = kt << 6;
#pragma unroll
    for (int j = 0; j < 2; j++) {
      int row  = j * 64 + sr;
      int slot = ss ^ (row & 7);
      load_lds16(Abase + (size_t)row * K + k0 + slot * 8, &lds[b][0][j * 4096 + t * 8]);
    }
#pragma unroll
    for (int j = 0; j < 2; j++) {
      int row  = j * 64 + sr;
      int slot = ss ^ (row & 7);
      load_lds16(Bbase + (size_t)row * K + k0 + slot * 8, &lds[b][1][j * 4096 + t * 8]);
    }
  };

  f32x16 acc0 = {};
  f32x16 acc1 = {};

  stage(0, 0);
  stage(1, 1);

  const int rowb = wn * 32 + l31;          // B row (loop-invariant)
  const int rowa0 = wm * 64 + l31;         // A row, mf0
  const int rowa1 = wm * 64 + 32 + l31;    // A row, mf1

  for (int tt = 0; tt < nt; tt++) {
    const int cur = tt & 1;
    if (tt + 1 < nt) asm volatile("s_waitcnt vmcnt(4)" ::: "memory");
    else             asm volatile("s_waitcnt vmcnt(0)" ::: "memory");
    __builtin_amdgcn_s_barrier();

    const u16* Ab = &lds[cur][0][0];
    const u16* Bb = &lds[cur][1][0];

    // ---- phase 1: B ks0..3 + A mf0 ks0..3 (k = ks*16 + hi*8) ----
    short8 bfr[4], afr[4];
#pragma unroll
    for (int ks = 0; ks < 4; ks++)
      bfr[ks] = *(const short8*)(Bb + rowb * 64 + (((ks * 2 + hi) ^ (rowb & 7)) << 3));
#pragma unroll
    for (int ks = 0; ks < 4; ks++)
      afr[ks] = *(const short8*)(Ab + rowa0 * 64 + (((ks * 2 + hi) ^ (rowa0 & 7)) << 3));
    asm volatile("s_waitcnt lgkmcnt(0)" ::: "memory");
    __builtin_amdgcn_sched_barrier(0);
    __builtin_amdgcn_s_setprio(1);
#pragma unroll
    for (int ks = 0; ks < 4; ks++)
      acc0 = __builtin_amdgcn_mfma_f32_32x32x16_bf16(bfr[ks], afr[ks], acc0, 0, 0, 0);
    __builtin_amdgcn_s_setprio(0);

    // ---- phase 2: A mf1 ks0..3 ----
    short8 afr2[4];
#pragma unroll
    for (int ks = 0; ks < 4; ks++)
      afr2[ks] = *(const short8*)(Ab + rowa1 * 64 + (((ks * 2 + hi) ^ (rowa1 & 7)) << 3));
    asm volatile("s_waitcnt lgkmcnt(0)" ::: "memory");
    __builtin_amdgcn_sched_barrier(0);
    __builtin_amdgcn_s_barrier();

    if (tt + 2 < nt) stage(tt + 2, cur);

    __builtin_amdgcn_s_setprio(1);
#pragma unroll
    for (int ks = 0; ks < 4; ks++)
      acc1 = __builtin_amdgcn_mfma_f32_32x32x16_bf16(bfr[ks], afr2[ks], acc1, 0, 0, 0);
    __builtin_amdgcn_s_setprio(0);
  }

  // swapped C/D (32x32): m = lane&31 (+mf*32), n = (reg&3) + 8*(reg>>2) + 4*hi
#pragma unroll
  for (int mf = 0; mf < 2; mf++) {
    size_t row = (size_t)(bm + wm * 64 + mf * 32 + l31);
#pragma unroll
    for (int g = 0; g < 4; g++) {
      int col0 = bn + wn * 32 + g * 8 + hi * 4;
      float4 b4 = *(const float4*)(bias + col0);
      float a0 = mf ? acc1[g * 4 + 0] : acc0[g * 4 + 0];
      float a1 = mf ? acc1[g * 4 + 1] : acc0[g * 4 + 1];
      float a2 = mf ? acc1[g * 4 + 2] : acc0[g * 4 + 2];
      float a3 = mf ? acc1[g * 4 + 3] : acc0[g * 4 + 3];
      float v0 = a0 + b4.x;
      float v1 = a1 + b4.y;
      float v2 = a2 + b4.z;
      float v3 = a3 + b4.w;
      if (RELU) {
        v0 = fmaxf(v0, 0.f); v1 = fmaxf(v1, 0.f);
        v2 = fmaxf(v2, 0.f); v3 = fmaxf(v3, 0.f);
      }
      if (RES) {
        short4v rv = *(const short4v*)(res + row * N + col0);
        v0 += bf2f((u16)rv[0]); v1 += bf2f((u16)rv[1]);
        v2 += bf2f((u16)rv[2]); v3 += bf2f((u16)rv[3]);
      }
      if (OUTBF) {
        short4v o;
        o[0] = (short)f2bf(v0); o[1] = (short)f2bf(v1);
        o[2] = (short)f2bf(v2); o[3] = (short)f2bf(v3);
        *(short4v*)((u16*)Cout + row * N + col0) = o;
      } else {
        f32x4 o = {v0, v1, v2, v3};
        *(f32x4*)((float*)Cout + row * N + col0) = o;
      }
    }
  }
}

// ---------------- conversions ----------------
__launch_bounds__(256)
__global__ void gather_x_bf16(const float* __restrict__ x, u16* __restrict__ xg)
{
  const int t = threadIdx.x, wv = t >> 6, lane = t & 63;
  const int r = blockIdx.x * 4 + wv;
  const float4* src = (const float4*)(x + (size_t)win_row_to_src(r) * CDIM);
  short4v* dst = (short4v*)(xg + (size_t)r * CDIM);
#pragma unroll
  for (int e = 0; e < 3; e++) {
    float4 f = src[e * 64 + lane];
    short4v o;
    o[0] = (short)f2bf(f.x); o[1] = (short)f2bf(f.y);
    o[2] = (short)f2bf(f.z); o[3] = (short)f2bf(f.w);
    dst[e * 64 + lane] = o;
  }
}

__launch_bounds__(256)
__global__ void conv4_bf16(const float* __restrict__ s0, const float* __restrict__ s1,
                           const float* __restrict__ s2, const float* __restrict__ s3,
                           u16* __restrict__ out)
{
  const int i = blockIdx.x * 256 + threadIdx.x;
  const int e = i * 4;
  const float* src; int off;
  if (e < 1769472)      { src = s0; off = 0; }
  else if (e < 2359296) { src = s1; off = 1769472; }
  else if (e < 4718592) { src = s2; off = 2359296; }
  else                  { src = s3; off = 4718592; }
  float4 f = *(const float4*)(src + (e - off));
  short4v o;
  o[0] = (short)f2bf(f.x); o[1] = (short)f2bf(f.y);
  o[2] = (short)f2bf(f.z); o[3] = (short)f2bf(f.w);
  *(short4v*)(out + e) = o;
}

// ---------------- MFMA attention (one wave per window-head) ----------------
__launch_bounds__(256)
__global__ void attn_mfma(const u16* __restrict__ qkv, const float* __restrict__ mask,
                          u16* __restrict__ out)
{
  __shared__ u16 vt[4][4096];
  __shared__ u16 pbuf[4][4096];
  __shared__ float ropetab[512];

  const int t = threadIdx.x;
  {
    int p = t >> 3, pos = t & 7;
    float inv = __expf(-(float)(p & 15) * 0.5756462732485115f);
    float sv, cv;
    sincosf((float)pos * inv, &sv, &cv);
    ropetab[t * 2]     = cv;
    ropetab[t * 2 + 1] = sv;
  }
  __syncthreads();

  const int wv = t >> 6, lane = t & 63;
  const int lr = lane & 15, lg = lane >> 4;
  const int gp   = blockIdx.x * 4 + wv;
  const int head = gp % 12;
  const int lw   = gp / 12;
  const int widx = lw % 288;
  const u16* base = qkv + (size_t)lw * 64 * QKVDIM + head * 64;

  {
    const u16* vrow = base + 1536 + (size_t)lane * QKVDIM;
    u16* vb = vt[wv];
#pragma unroll
    for (int s = 0; s < 8; s++) {
      short8 v = *(const short8*)(vrow + s * 8);
#pragma unroll
      for (int j = 0; j < 8; j++) {
        int d = s * 8 + j;
        vb[d * 64 + ((((lane >> 3) ^ (d & 7)) << 3) | (lane & 7))] = (u16)v[j];
      }
    }
  }

  short8 aq[4][2], ak[4][2];
#pragma unroll
  for (int f = 0; f < 4; f++) {
#pragma unroll
    for (int ks = 0; ks < 2; ks++) {
      int n = f * 16 + lr;
      short8 qv = *(const short8*)(base + (size_t)n * QKVDIM + ks * 32 + lg * 8);
      short8 kv = *(const short8*)(base + (size_t)n * QKVDIM + 768 + ks * 32 + lg * 8);
      short8 qo, ko;
#pragma unroll
      for (int jj = 0; jj < 4; jj++) {
        int p   = ks * 16 + lg * 4 + jj;
        int pos = (p < 16) ? (n >> 3) : (n & 7);
        float cv = ropetab[(p * 8 + pos) * 2];
        float sv = ropetab[(p * 8 + pos) * 2 + 1];
        float q1 = bf2f((u16)qv[2 * jj]), q2 = bf2f((u16)qv[2 * jj + 1]);
        float k1 = bf2f((u16)kv[2 * jj]), k2 = bf2f((u16)kv[2 * jj + 1]);
        qo[2 * jj]     = (short)f2bf((q1 * cv - q2 * sv) * 0.125f);
        qo[2 * jj + 1] = (short)f2bf((q1 * sv + q2 * cv) * 0.125f);
        ko[2 * jj]     = (short)f2bf(k1 * cv - k2 * sv);
        ko[2 * jj + 1] = (short)f2bf(k1 * sv + k2 * cv);
      }
      aq[f][ks] = qo; ak[f][ks] = ko;
    }
  }

  f32x4 sf[4][4] = {};
#pragma unroll
  for (int ks = 0; ks < 2; ks++)
#pragma unroll
    for (int fn = 0; fn < 4; fn++)
#pragma unroll
      for (int fm = 0; fm < 4; fm++)
        sf[fn][fm] = __builtin_amdgcn_mfma_f32_16x16x32_bf16(aq[fn][ks], ak[fm][ks], sf[fn][fm], 0, 0, 0);

  const float* mrow = mask + (size_t)widx * 4096;
#pragma unroll
  for (int fn = 0; fn < 4; fn++)
#pragma unroll
    for (int fm = 0; fm < 4; fm++)
#pragma unroll
      for (int j = 0; j < 4; j++)
        sf[fn][fm][j] += mrow[(fn * 16 + lg * 4 + j) * 64 + fm * 16 + lr];

#pragma unroll
  for (int fn = 0; fn < 4; fn++) {
#pragma unroll
    for (int j = 0; j < 4; j++) {
      float m0 = fmaxf(fmaxf(sf[fn][0][j], sf[fn][1][j]),
                       fmaxf(sf[fn][2][j], sf[fn][3][j]));
      m0 = fmaxf(m0, __shfl_xor(m0, 1));
      m0 = fmaxf(m0, __shfl_xor(m0, 2));
      m0 = fmaxf(m0, __shfl_xor(m0, 4));
      m0 = fmaxf(m0, __shfl_xor(m0, 8));
      float s0 = 0.f;
#pragma unroll
      for (int fm = 0; fm < 4; fm++) {
        float e = __expf(sf[fn][fm][j] - m0);
        sf[fn][fm][j] = e;
        s0 += e;
      }
      s0 += __shfl_xor(s0, 1);
      s0 += __shfl_xor(s0, 2);
      s0 += __shfl_xor(s0, 4);
      s0 += __shfl_xor(s0, 8);
      float r = 1.f / s0;
#pragma unroll
      for (int fm = 0; fm < 4; fm++) sf[fn][fm][j] *= r;
    }
  }

  u16* pb = pbuf[wv];
#pragma unroll
  for (int fn = 0; fn < 4; fn++)
#pragma unroll
    for (int fm = 0; fm < 4; fm++)
#pragma unroll
      for (int j = 0; j < 4; j++) {
        int n = fn * 16 + lg * 4 + j, m = fm * 16 + lr;
        pb[n * 64 + ((((m >> 3) ^ (n & 7)) << 3) | (m & 7))] = f2bf(sf[fn][fm][j]);
      }
  asm volatile("s_waitcnt lgkmcnt(0)" ::: "memory");
  __builtin_amdgcn_sched_barrier(0);

  short8 ap[4][2], bvf[4][2];
#pragma unroll
  for (int f = 0; f < 4; f++)
#pragma unroll
    for (int ks = 0; ks < 2; ks++) {
      int rn = f * 16 + lr;
      ap[f][ks]  = *(const short8*)(pb     + rn * 64 + (((ks * 4 + lg) ^ (rn & 7)) << 3));
      bvf[f][ks] = *(const short8*)(vt[wv] + rn * 64 + (((ks * 4 + lg) ^ (rn & 7)) << 3));
    }
  f32x4 o[4][4] = {};
#pragma unroll
  for (int ks = 0; ks < 2; ks++)
#pragma unroll
    for (int fn = 0; fn < 4; fn++)
#pragma unroll
      for (int fd = 0; fd < 4; fd++)
        o[fn][fd] = __builtin_amdgcn_mfma_f32_16x16x32_bf16(bvf[fd][ks], ap[fn][ks], o[fn][fd], 0, 0, 0);

  u16* ob = out + ((size_t)lw * 64) * CDIM + head * 64;
#pragma unroll
  for (int fn = 0; fn < 4; fn++) {
    size_t nrow = (size_t)(fn * 16 + lr) * CDIM;
#pragma unroll
    for (int fd = 0; fd < 4; fd++) {
      int d0 = fd * 16 + lg * 4;
      short4v ov;
      ov[0] = (short)f2bf(o[fn][fd][0]);
      ov[1] = (short)f2bf(o[fn][fd][1]);
      ov[2] = (short)f2bf(o[fn][fd][2]);
      ov[3] = (short)f2bf(o[fn][fd][3]);
      *(short4v*)(ob + nrow + d0) = ov;
    }
  }
}

// ---------------- LayerNorms (wave-per-token, shfl reduction) ----------------
__launch_bounds__(256)
__global__ void ln1_kernel(const u16* __restrict__ xg, const u16* __restrict__ add,
                           const float* __restrict__ g, const float* __restrict__ bb,
                           u16* __restrict__ out)
{
  const int t = threadIdx.x, wv = t >> 6, lane = t & 63;
  const int tok = blockIdx.x * 4 + wv;
  int b = tok / 18432;
  int hw = tok - b * 18432;
  int h = hw / 192, w = hw - h * 192;
  int h2 = h - 4; if (h2 < 0) h2 += 96;
  int w2 = w - 4; if (w2 < 0) w2 += 192;
  int r = ((b * 12 + (h2 >> 3)) * 24 + (w2 >> 3)) * 64 + (h2 & 7) * 8 + (w2 & 7);
  const short4v* a0 = (const short4v*)(xg  + (size_t)r * CDIM);
  const short4v* a1 = (const short4v*)(add + (size_t)r * CDIM);

  float v[12];
  float s1 = 0.f, s2 = 0.f;
#pragma unroll
  for (int e = 0; e < 3; e++) {
    short4v f = a0[e * 64 + lane];
    short4v a = a1[e * 64 + lane];
#pragma unroll
    for (int j = 0; j < 4; j++) {
      float x = bf2f((u16)f[j]) + bf2f((u16)a[j]);
      v[e*4+j] = x; s1 += x; s2 += x * x;
    }
  }
#pragma unroll
  for (int m = 1; m < 64; m <<= 1) {
    s1 += __shfl_xor(s1, m);
    s2 += __shfl_xor(s2, m);
  }
  float mean = s1 * (1.f / 768.f);
  float var  = s2 * (1.f / 768.f) - mean * mean;
  float rs   = rsqrtf(var + 1e-5f);
  short4v* dst = (short4v*)(out + (size_t)tok * CDIM);
#pragma unroll
  for (int e = 0; e < 3; e++) {
    short4v o;
#pragma unroll
    for (int j = 0; j < 4; j++) {
      int c = (e * 64 + lane) * 4 + j;
      o[j] = (short)f2bf((v[e*4+j] - mean) * rs * g[c] + bb[c]);
    }
    dst[e * 64 + lane] = o;
  }
}

__launch_bounds__(256)
__global__ void ln2_kernel(const u16* __restrict__ xin, const float* __restrict__ g,
                           const float* __restrict__ bb, float* __restrict__ out)
{
  const int t = threadIdx.x, wv = t >> 6, lane = t & 63;
  const int tok = blockIdx.x * 4 + wv;
  const short4v* a0 = (const short4v*)(xin + (size_t)tok * CDIM);

  float v[12];
  float s1 = 0.f, s2 = 0.f;
#pragma unroll
  for (int e = 0; e < 3; e++) {
    short4v a = a0[e * 64 + lane];
#pragma unroll
    for (int j = 0; j < 4; j++) {
      float x = bf2f((u16)a[j]);
      v[e*4+j] = x; s1 += x; s2 += x * x;
    }
  }
#pragma unroll
  for (int m = 1; m < 64; m <<= 1) {
    s1 += __shfl_xor(s1, m);
    s2 += __shfl_xor(s2, m);
  }
  float mean = s1 * (1.f / 768.f);
  float var  = s2 * (1.f / 768.f) - mean * mean;
  float rs   = rsqrtf(var + 1e-5f);
  float4* dst = (float4*)(out + (size_t)tok * CDIM);
#pragma unroll
  for (int e = 0; e < 3; e++) {
    float4 o;
    int c = (e * 64 + lane) * 4;
    o.x = (v[e*4+0] - mean) * rs * g[c+0] + bb[c+0];
    o.y = (v[e*4+1] - mean) * rs * g[c+1] + bb[c+1];
    o.z = (v[e*4+2] - mean) * rs * g[c+2] + bb[c+2];
    o.w = (v[e*4+3] - mean) * rs * g[c+3] + bb[c+3];
    dst[e * 64 + lane] = o;
  }
}

static inline void launch_gemm(const u16* A, const u16* Wt, const float* bias,
                               const u16* res, void* C, int M, int N, int K,
                               int outbf, int relu, int resf, hipStream_t s)
{
  int gridx = N / 128, nwg = gridx * (M / 128);
  if (outbf) {
    if (relu)      gemm128<1,1,0><<<nwg, 512, 0, s>>>(A, Wt, bias, res, C, M, N, K, gridx, nwg);
    else if (resf) gemm128<1,0,1><<<nwg, 512, 0, s>>>(A, Wt, bias, res, C, M, N, K, gridx, nwg);
    else           gemm128<1,0,0><<<nwg, 512, 0, s>>>(A, Wt, bias, res, C, M, N, K, gridx, nwg);
  } else {
    gemm128<0,0,0><<<nwg, 512, 0, s>>>(A, Wt, bias, res, C, M, N, K, gridx, nwg);
  }
}

static inline void launch_gemm_w(const u16* A, const u16* Wt, const float* bias,
                                 const u16* res, void* C, int M, int N, int K,
                                 int relu, int resf, hipStream_t s)
{
  int gridx = N / 128, nwg = gridx * (M / 128);
  if (relu)      gemm128w<1,1,0><<<nwg, 512, 0, s>>>(A, Wt, bias, res, C, M, N, K, gridx, nwg);
  else if (resf) gemm128w<1,0,1><<<nwg, 512, 0, s>>>(A, Wt, bias, res, C, M, N, K, gridx, nwg);
  else           gemm128w<1,0,0><<<nwg, 512, 0, s>>>(A, Wt, bias, res, C, M, N, K, gridx, nwg);
}

extern "C" void kernel_launch(void* const* d_in, const int* in_sizes, int n_in,
                              void* d_out, int out_size, void* d_ws, size_t ws_size,
                              hipStream_t stream)
{
  const float* x      = (const float*)d_in[0];
  const float* mask   = (const float*)d_in[1];
  const float* w_qkv  = (const float*)d_in[2];
  const float* b_qkv  = (const float*)d_in[3];
  const float* w_proj = (const float*)d_in[4];
  const float* b_proj = (const float*)d_in[5];
  const float* g1     = (const float*)d_in[6];
  const float* b1     = (const float*)d_in[7];
  const float* g2     = (const float*)d_in[8];
  const float* b2     = (const float*)d_in[9];
  const float* w_fc1  = (const float*)d_in[10];
  const float* b_fc1  = (const float*)d_in[11];
  const float* w_fc2  = (const float*)d_in[12];
  const float* b_fc2  = (const float*)d_in[13];
  float* out = (float*)d_out;

  // ws layout, total 297,271,296 B:
  //  A0 [0, 56.6M):        xg -> h[0:56.6M)
  //  A1 [56.6M, 226.5M):   QKV -> proj-out -> h[56.6M:226.5M)
  //  A2 [226.5M, 283.1M):  AO -> x1 -> y (in-place)
  //  W  [283.1M, 297.3M):  bf16 weights (contiguous: qkv|proj|fc1|fc2)
  char* base = (char*)d_ws;
  u16* A0 = (u16*)base;
  u16* A1 = (u16*)(base + 56623104);
  u16* A2 = (u16*)(base + 226492416);
  u16* Hb = (u16*)base;
  u16* wqkvb  = (u16*)(base + 283115520);
  u16* wprojb = wqkvb  + 1769472;
  u16* wfc1b  = wprojb + 589824;
  u16* wfc2b  = wfc1b  + 2359296;

  conv4_bf16<<<1769472 / 256, 256, 0, stream>>>(w_qkv, w_proj, w_fc1, w_fc2, wqkvb);
  gather_x_bf16<<<NTOK / 4, 256, 0, stream>>>(x, A0);

  // QKV (gemm128 control) then attention
  launch_gemm(A0, wqkvb, b_qkv, nullptr, A1, NTOK, QKVDIM, CDIM, 1, 0, 0, stream);
  attn_mfma<<<576 * 12 / 4, 256, 0, stream>>>(A1, mask, A2);

  // proj (gemm128 control)
  launch_gemm(A2, wprojb, b_proj, nullptr, A1, NTOK, CDIM, CDIM, 1, 0, 0, stream);

  // LN1
  ln1_kernel<<<NTOK / 4, 256, 0, stream>>>(A0, A1, g1, b1, A2);

  // MLP on the 32x32-MFMA kernel (experiment)
  launch_gemm_w(A2, wfc1b, b_fc1, nullptr, Hb, NTOK, HIDDIM, CDIM, 1, 0, stream);
  launch_gemm_w(Hb, wfc2b, b_fc2, A2, A2, NTOK, CDIM, HIDDIM, 0, 1, stream);

  // LN2 -> out (fp32)
  ln2_kernel<<<NTOK / 4, 256, 0, stream>>>(A2, g2, b2, out);
}

// Round 18
// 849.224 us; speedup vs baseline: 1.6221x; 1.0781x over previous
//
#include <hip/hip_runtime.h>
#include <math.h>
#include <stddef.h>

// B=2, H=96, W=192, C=768, NH=12, HD=64, W0=W1=8, S0=S1=4, N=64,
// NW=288 windows/image, B_=576 windows, tokens=36864, HID=3072
#define NTOK   36864
#define CDIM   768
#define HIDDIM 3072
#define QKVDIM 2304

typedef unsigned short u16;
typedef unsigned int   u32;
typedef __attribute__((ext_vector_type(8))) short short8;   // 8 bf16 (4 VGPRs)
typedef __attribute__((ext_vector_type(4))) short short4v;  // 4 bf16
typedef __attribute__((ext_vector_type(4))) float f32x4;

__device__ __forceinline__ float bf2f(u16 h) { return __uint_as_float(((u32)h) << 16); }
__device__ __forceinline__ u16 f2bf(float f) {
  u32 u = __float_as_uint(f);
  u32 r = u + 0x7fffu + ((u >> 16) & 1u);      // RNE
  return (u16)(r >> 16);
}

// window-order row r (0..36863) -> spatial token index (roll -4,-4 + partition)
__device__ __forceinline__ int win_row_to_src(int r) {
  int n = r & 63;
  int wflat = r >> 6;
  int b = wflat / 288;
  int wi = wflat - b * 288;
  int wh = wi / 24;
  int ww = wi - wh * 24;
  int i0 = n >> 3, i1 = n & 7;
  int hh = wh * 8 + i0 + 4; if (hh >= 96)  hh -= 96;
  int wp = ww * 8 + i1 + 4; if (wp >= 192) wp -= 192;
  return b * 18432 + hh * 192 + wp;
}

__device__ __forceinline__ void load_lds16(const u16* g, u16* l) {
  __builtin_amdgcn_global_load_lds((const __attribute__((address_space(1))) void*)g,
                                   (__attribute__((address_space(3))) void*)l, 16, 0, 0);
}

// ---------------- 128x128 bf16 MFMA GEMM, 8 waves, 2 blocks/CU ----------------
// (round-11/13/15 configuration: measured best, SQ_LDS_BANK_CONFLICT = 0)
// C[M,N] = A[M,K](bf16) @ Wt[N,K](bf16)^T + bias (+RELU) (+bf16 res)
// 8 waves (512 thr), wave (wm,wn)=(wv>>2,wv&3) owns 64x32 out (4 Mf x 2 Nf).
// launch_bounds(512,4) caps regs at 128 -> 2 blocks x 8 waves = 4 waves/SIMD.
// LDS 2 buf x (A[128][64]+B[128][64]) = 64 KiB; slot swizzle slot^=(row&7)
// on BOTH gload_lds source and ds_read (rule 21). 2 barriers/tile; counted
// vmcnt(4) (never 0 mid-loop); setprio (T5); swapped-operand MFMA -> 8B stores.
// Grid: m204 XCD chunk map, bn-fastest; banded N-halves when gridx,nwg even.
// Session note: plateau at MfmaUtil ~33.7% is the 2-barrier structure's
// stage+vmcnt+barrier serialization (m233); 8-phase (x2), B-direct, and
// 32x32-shape escapes all measured worse -> this is the banked best.
template<int OUTBF, int RELU, int RES>
__launch_bounds__(512, 4)
__global__ void gemm128(const u16* __restrict__ A, const u16* __restrict__ Wt,
                        const float* __restrict__ bias, const u16* __restrict__ res,
                        void* __restrict__ Cout, int M, int N, int K,
                        int gridx, int nwg)
{
  // bijective XCD chunk map (m204)
  const int orig = blockIdx.x;
  const int xcd  = orig & 7;
  const int q    = nwg >> 3, r8 = nwg & 7;
  const int wgid = (xcd < r8 ? xcd * (q + 1) : r8 * (q + 1) + (xcd - r8) * q) + (orig >> 3);
  int bn, bm;
  if (((gridx | nwg) & 1) == 0) {            // banded decode
    const int halfn = nwg >> 1, hc = gridx >> 1;
    const int half  = (wgid >= halfn) ? 1 : 0;
    const int w2    = wgid - half * halfn;
    bn = (w2 % hc + half * hc) * 128;
    bm = (w2 / hc) * 128;
  } else {                                    // plain bn-fastest
    bn = (wgid % gridx) * 128;
    bm = (wgid / gridx) * 128;
  }

  __shared__ __align__(16) u16 lds[2][2][128 * 64];   // [buf][A=0/B=1][row*64+k] = 64 KiB

  const int t    = threadIdx.x;
  const int wv   = t >> 6, lane = t & 63;
  const int wm   = wv >> 2, wn = wv & 3;    // 2M x 4N
  const int lr   = lane & 15, lg = lane >> 4;
  const int sr   = t >> 3;          // staging row within 64-row group (0..63)
  const int ss   = t & 7;           // staging slot (0..7)

  const u16* Abase = A  + (size_t)bm * K;
  const u16* Bbase = Wt + (size_t)bn * K;

  const int nt = K >> 6;            // K-tiles (12 or 48 here)

  // stage K-tile kt into buffer b: 2 A-issues + 2 B-issues of 16B/lane (4/thread)
  auto stage = [&](int kt, int b) {
    const int k0 = kt << 6;
#pragma unroll
    for (int j = 0; j < 2; j++) {
      int row  = j * 64 + sr;
      int slot = ss ^ (row & 7);
      load_lds16(Abase + (size_t)row * K + k0 + slot * 8, &lds[b][0][j * 4096 + t * 8]);
    }
#pragma unroll
    for (int j = 0; j < 2; j++) {
      int row  = j * 64 + sr;
      int slot = ss ^ (row & 7);
      load_lds16(Bbase + (size_t)row * K + k0 + slot * 8, &lds[b][1][j * 4096 + t * 8]);
    }
  };

  f32x4 acc[4][2] = {};

  stage(0, 0);
  stage(1, 1);

  for (int tt = 0; tt < nt; tt++) {
    const int cur = tt & 1;
    if (tt + 1 < nt) asm volatile("s_waitcnt vmcnt(4)" ::: "memory");
    else             asm volatile("s_waitcnt vmcnt(0)" ::: "memory");
    __builtin_amdgcn_s_barrier();            // buf[cur] visible to all waves

    const u16* Ab = &lds[cur][0][0];
    const u16* Bb = &lds[cur][1][0];

    // ---- phase 1: all B-frags + A-frags mf 0..1 ----
    short8 bfr[2][2], afr[2][2];
#pragma unroll
    for (int nf = 0; nf < 2; nf++)
#pragma unroll
      for (int ks = 0; ks < 2; ks++) {
        int row = wn * 32 + nf * 16 + lr;
        bfr[nf][ks] = *(const short8*)(Bb + row * 64 + (((ks * 4 + lg) ^ (row & 7)) << 3));
      }
#pragma unroll
    for (int mf = 0; mf < 2; mf++)
#pragma unroll
      for (int ks = 0; ks < 2; ks++) {
        int row = wm * 64 + mf * 16 + lr;
        afr[mf][ks] = *(const short8*)(Ab + row * 64 + (((ks * 4 + lg) ^ (row & 7)) << 3));
      }
    asm volatile("s_waitcnt lgkmcnt(0)" ::: "memory");
    __builtin_amdgcn_sched_barrier(0);
    __builtin_amdgcn_s_setprio(1);
#pragma unroll
    for (int ks = 0; ks < 2; ks++)
#pragma unroll
      for (int mf = 0; mf < 2; mf++)
#pragma unroll
        for (int nf = 0; nf < 2; nf++)
          acc[mf][nf] = __builtin_amdgcn_mfma_f32_16x16x32_bf16(bfr[nf][ks], afr[mf][ks], acc[mf][nf], 0, 0, 0);
    __builtin_amdgcn_s_setprio(0);

    // ---- phase 2: A-frags mf 2..3 ----
    short8 afr2[2][2];
#pragma unroll
    for (int mf = 0; mf < 2; mf++)
#pragma unroll
      for (int ks = 0; ks < 2; ks++) {
        int row = wm * 64 + (mf + 2) * 16 + lr;
        afr2[mf][ks] = *(const short8*)(Ab + row * 64 + (((ks * 4 + lg) ^ (row & 7)) << 3));
      }
    asm volatile("s_waitcnt lgkmcnt(0)" ::: "memory");
    __builtin_amdgcn_sched_barrier(0);
    __builtin_amdgcn_s_barrier();            // all waves done reading buf[cur]

    if (tt + 2 < nt) stage(tt + 2, cur);     // overwrite buf[cur]; hides under MFMA

    __builtin_amdgcn_s_setprio(1);
#pragma unroll
    for (int ks = 0; ks < 2; ks++)
#pragma unroll
      for (int mf = 0; mf < 2; mf++)
#pragma unroll
        for (int nf = 0; nf < 2; nf++)
          acc[mf + 2][nf] = __builtin_amdgcn_mfma_f32_16x16x32_bf16(bfr[nf][ks], afr2[mf][ks], acc[mf + 2][nf], 0, 0, 0);
    __builtin_amdgcn_s_setprio(0);
  }

  // swapped C/D: per lane row m = lr, cols n = lg*4 + j (4 consecutive)
#pragma unroll
  for (int mf = 0; mf < 4; mf++) {
    size_t row = (size_t)(bm + wm * 64 + mf * 16 + lr);
#pragma unroll
    for (int nf = 0; nf < 2; nf++) {
      int col0 = bn + wn * 32 + nf * 16 + lg * 4;
      float4 b4 = *(const float4*)(bias + col0);
      float v0 = acc[mf][nf][0] + b4.x;
      float v1 = acc[mf][nf][1] + b4.y;
      float v2 = acc[mf][nf][2] + b4.z;
      float v3 = acc[mf][nf][3] + b4.w;
      if (RELU) {
        v0 = fmaxf(v0, 0.f); v1 = fmaxf(v1, 0.f);
        v2 = fmaxf(v2, 0.f); v3 = fmaxf(v3, 0.f);
      }
      if (RES) {
        short4v rv = *(const short4v*)(res + row * N + col0);
        v0 += bf2f((u16)rv[0]); v1 += bf2f((u16)rv[1]);
        v2 += bf2f((u16)rv[2]); v3 += bf2f((u16)rv[3]);
      }
      if (OUTBF) {
        short4v o;
        o[0] = (short)f2bf(v0); o[1] = (short)f2bf(v1);
        o[2] = (short)f2bf(v2); o[3] = (short)f2bf(v3);
        *(short4v*)((u16*)Cout + row * N + col0) = o;
      } else {
        f32x4 o = {v0, v1, v2, v3};
        *(f32x4*)((float*)Cout + row * N + col0) = o;
      }
    }
  }
}

// ---------------- conversions ----------------
// wave-per-row gather: 4 rows/block, float4 in, bf16x4 out
__launch_bounds__(256)
__global__ void gather_x_bf16(const float* __restrict__ x, u16* __restrict__ xg)
{
  const int t = threadIdx.x, wv = t >> 6, lane = t & 63;
  const int r = blockIdx.x * 4 + wv;
  const float4* src = (const float4*)(x + (size_t)win_row_to_src(r) * CDIM);
  short4v* dst = (short4v*)(xg + (size_t)r * CDIM);
#pragma unroll
  for (int e = 0; e < 3; e++) {
    float4 f = src[e * 64 + lane];
    short4v o;
    o[0] = (short)f2bf(f.x); o[1] = (short)f2bf(f.y);
    o[2] = (short)f2bf(f.z); o[3] = (short)f2bf(f.w);
    dst[e * 64 + lane] = o;
  }
}

// merged 4-weight fp32->bf16 conversion (outputs contiguous in ws)
// sizes: w_qkv 1769472 | w_proj 589824 | w_fc1 2359296 | w_fc2 2359296
__launch_bounds__(256)
__global__ void conv4_bf16(const float* __restrict__ s0, const float* __restrict__ s1,
                           const float* __restrict__ s2, const float* __restrict__ s3,
                           u16* __restrict__ out)
{
  const int i = blockIdx.x * 256 + threadIdx.x;   // float4 index, 1769472 total
  const int e = i * 4;
  const float* src; int off;
  if (e < 1769472)      { src = s0; off = 0; }
  else if (e < 2359296) { src = s1; off = 1769472; }
  else if (e < 4718592) { src = s2; off = 2359296; }
  else                  { src = s3; off = 4718592; }
  float4 f = *(const float4*)(src + (e - off));
  short4v o;
  o[0] = (short)f2bf(f.x); o[1] = (short)f2bf(f.y);
  o[2] = (short)f2bf(f.z); o[3] = (short)f2bf(f.w);
  *(short4v*)(out + e) = o;
}

// ---------------- MFMA attention (one wave per window-head) ----------------
__launch_bounds__(256)
__global__ void attn_mfma(const u16* __restrict__ qkv, const float* __restrict__ mask,
                          u16* __restrict__ out)
{
  __shared__ u16 vt[4][4096];        // V^T per wave: [d][m]
  __shared__ u16 pbuf[4][4096];      // P per wave: [n][m]
  __shared__ float ropetab[512];     // (cos,sin) for (p in 0..31, pos in 0..7)

  const int t = threadIdx.x;
  {
    int p = t >> 3, pos = t & 7;
    float inv = __expf(-(float)(p & 15) * 0.5756462732485115f);  // 10000^(-(p&15)/16)
    float sv, cv;
    sincosf((float)pos * inv, &sv, &cv);
    ropetab[t * 2]     = cv;
    ropetab[t * 2 + 1] = sv;
  }
  __syncthreads();

  const int wv = t >> 6, lane = t & 63;
  const int lr = lane & 15, lg = lane >> 4;
  const int gp   = blockIdx.x * 4 + wv;
  const int head = gp % 12;
  const int lw   = gp / 12;          // global window 0..575
  const int widx = lw % 288;
  const u16* base = qkv + (size_t)lw * 64 * QKVDIM + head * 64;

  // --- stage V^T: lane reads V row m=lane (64 d), scatters to vt[d][m] ---
  {
    const u16* vrow = base + 1536 + (size_t)lane * QKVDIM;
    u16* vb = vt[wv];
#pragma unroll
    for (int s = 0; s < 8; s++) {
      short8 v = *(const short8*)(vrow + s * 8);
#pragma unroll
      for (int j = 0; j < 8; j++) {
        int d = s * 8 + j;
        vb[d * 64 + ((((lane >> 3) ^ (d & 7)) << 3) | (lane & 7))] = (u16)v[j];
      }
    }
  }

  // --- load Q,K fragments with RoPE ---
  short8 aq[4][2], ak[4][2];
#pragma unroll
  for (int f = 0; f < 4; f++) {
#pragma unroll
    for (int ks = 0; ks < 2; ks++) {
      int n = f * 16 + lr;
      short8 qv = *(const short8*)(base + (size_t)n * QKVDIM + ks * 32 + lg * 8);
      short8 kv = *(const short8*)(base + (size_t)n * QKVDIM + 768 + ks * 32 + lg * 8);
      short8 qo, ko;
#pragma unroll
      for (int jj = 0; jj < 4; jj++) {
        int p   = ks * 16 + lg * 4 + jj;
        int pos = (p < 16) ? (n >> 3) : (n & 7);
        float cv = ropetab[(p * 8 + pos) * 2];
        float sv = ropetab[(p * 8 + pos) * 2 + 1];
        float q1 = bf2f((u16)qv[2 * jj]), q2 = bf2f((u16)qv[2 * jj + 1]);
        float k1 = bf2f((u16)kv[2 * jj]), k2 = bf2f((u16)kv[2 * jj + 1]);
        qo[2 * jj]     = (short)f2bf((q1 * cv - q2 * sv) * 0.125f);
        qo[2 * jj + 1] = (short)f2bf((q1 * sv + q2 * cv) * 0.125f);
        ko[2 * jj]     = (short)f2bf(k1 * cv - k2 * sv);
        ko[2 * jj + 1] = (short)f2bf(k1 * sv + k2 * cv);
      }
      aq[f][ks] = qo; ak[f][ks] = ko;
    }
  }

  // --- S = Q K^T ---
  f32x4 sf[4][4] = {};
#pragma unroll
  for (int ks = 0; ks < 2; ks++)
#pragma unroll
    for (int fn = 0; fn < 4; fn++)
#pragma unroll
      for (int fm = 0; fm < 4; fm++)
        sf[fn][fm] = __builtin_amdgcn_mfma_f32_16x16x32_bf16(aq[fn][ks], ak[fm][ks], sf[fn][fm], 0, 0, 0);

  // --- + mask ---
  const float* mrow = mask + (size_t)widx * 4096;
#pragma unroll
  for (int fn = 0; fn < 4; fn++)
#pragma unroll
    for (int fm = 0; fm < 4; fm++)
#pragma unroll
      for (int j = 0; j < 4; j++)
        sf[fn][fm][j] += mrow[(fn * 16 + lg * 4 + j) * 64 + fm * 16 + lr];

  // --- softmax over m ---
#pragma unroll
  for (int fn = 0; fn < 4; fn++) {
#pragma unroll
    for (int j = 0; j < 4; j++) {
      float m0 = fmaxf(fmaxf(sf[fn][0][j], sf[fn][1][j]),
                       fmaxf(sf[fn][2][j], sf[fn][3][j]));
      m0 = fmaxf(m0, __shfl_xor(m0, 1));
      m0 = fmaxf(m0, __shfl_xor(m0, 2));
      m0 = fmaxf(m0, __shfl_xor(m0, 4));
      m0 = fmaxf(m0, __shfl_xor(m0, 8));
      float s0 = 0.f;
#pragma unroll
      for (int fm = 0; fm < 4; fm++) {
        float e = __expf(sf[fn][fm][j] - m0);
        sf[fn][fm][j] = e;
        s0 += e;
      }
      s0 += __shfl_xor(s0, 1);
      s0 += __shfl_xor(s0, 2);
      s0 += __shfl_xor(s0, 4);
      s0 += __shfl_xor(s0, 8);
      float r = 1.f / s0;
#pragma unroll
      for (int fm = 0; fm < 4; fm++) sf[fn][fm][j] *= r;
    }
  }

  // --- write P[n][m] bf16 to LDS (swizzled slots) ---
  u16* pb = pbuf[wv];
#pragma unroll
  for (int fn = 0; fn < 4; fn++)
#pragma unroll
    for (int fm = 0; fm < 4; fm++)
#pragma unroll
      for (int j = 0; j < 4; j++) {
        int n = fn * 16 + lg * 4 + j, m = fm * 16 + lr;
        pb[n * 64 + ((((m >> 3) ^ (n & 7)) << 3) | (m & 7))] = f2bf(sf[fn][fm][j]);
      }
  asm volatile("s_waitcnt lgkmcnt(0)" ::: "memory");   // wave-local LDS drain
  __builtin_amdgcn_sched_barrier(0);

  // --- O = P V, swapped: o = mfma(V^T-frag, P-frag) -> C[d(reg)][n(lane)] ---
  short8 ap[4][2], bvf[4][2];
#pragma unroll
  for (int f = 0; f < 4; f++)
#pragma unroll
    for (int ks = 0; ks < 2; ks++) {
      int rn = f * 16 + lr;
      ap[f][ks]  = *(const short8*)(pb     + rn * 64 + (((ks * 4 + lg) ^ (rn & 7)) << 3));
      bvf[f][ks] = *(const short8*)(vt[wv] + rn * 64 + (((ks * 4 + lg) ^ (rn & 7)) << 3));
    }
  f32x4 o[4][4] = {};
#pragma unroll
  for (int ks = 0; ks < 2; ks++)
#pragma unroll
    for (int fn = 0; fn < 4; fn++)
#pragma unroll
      for (int fd = 0; fd < 4; fd++)
        o[fn][fd] = __builtin_amdgcn_mfma_f32_16x16x32_bf16(bvf[fd][ks], ap[fn][ks], o[fn][fd], 0, 0, 0);

  // per lane: row n = fn*16 + lr, cols d = fd*16 + lg*4 + j -> 8B stores
  u16* ob = out + ((size_t)lw * 64) * CDIM + head * 64;
#pragma unroll
  for (int fn = 0; fn < 4; fn++) {
    size_t nrow = (size_t)(fn * 16 + lr) * CDIM;
#pragma unroll
    for (int fd = 0; fd < 4; fd++) {
      int d0 = fd * 16 + lg * 4;
      short4v ov;
      ov[0] = (short)f2bf(o[fn][fd][0]);
      ov[1] = (short)f2bf(o[fn][fd][1]);
      ov[2] = (short)f2bf(o[fn][fd][2]);
      ov[3] = (short)f2bf(o[fn][fd][3]);
      *(short4v*)(ob + nrow + d0) = ov;
    }
  }
}

// ---------------- LayerNorms (wave-per-token, shfl reduction) ----------------
// LN1: in = xg[r](bf16) + proj[r](bf16), r = win_row(tok); out x1[tok] bf16.
__launch_bounds__(256)
__global__ void ln1_kernel(const u16* __restrict__ xg, const u16* __restrict__ add,
                           const float* __restrict__ g, const float* __restrict__ bb,
                           u16* __restrict__ out)
{
  const int t = threadIdx.x, wv = t >> 6, lane = t & 63;
  const int tok = blockIdx.x * 4 + wv;
  int b = tok / 18432;
  int hw = tok - b * 18432;
  int h = hw / 192, w = hw - h * 192;
  int h2 = h - 4; if (h2 < 0) h2 += 96;
  int w2 = w - 4; if (w2 < 0) w2 += 192;
  int r = ((b * 12 + (h2 >> 3)) * 24 + (w2 >> 3)) * 64 + (h2 & 7) * 8 + (w2 & 7);
  const short4v* a0 = (const short4v*)(xg  + (size_t)r * CDIM);
  const short4v* a1 = (const short4v*)(add + (size_t)r * CDIM);

  float v[12];
  float s1 = 0.f, s2 = 0.f;
#pragma unroll
  for (int e = 0; e < 3; e++) {
    short4v f = a0[e * 64 + lane];
    short4v a = a1[e * 64 + lane];
#pragma unroll
    for (int j = 0; j < 4; j++) {
      float x = bf2f((u16)f[j]) + bf2f((u16)a[j]);
      v[e*4+j] = x; s1 += x; s2 += x * x;
    }
  }
#pragma unroll
  for (int m = 1; m < 64; m <<= 1) {
    s1 += __shfl_xor(s1, m);
    s2 += __shfl_xor(s2, m);
  }
  float mean = s1 * (1.f / 768.f);
  float var  = s2 * (1.f / 768.f) - mean * mean;
  float rs   = rsqrtf(var + 1e-5f);
  short4v* dst = (short4v*)(out + (size_t)tok * CDIM);
#pragma unroll
  for (int e = 0; e < 3; e++) {
    short4v o;
#pragma unroll
    for (int j = 0; j < 4; j++) {
      int c = (e * 64 + lane) * 4 + j;
      o[j] = (short)f2bf((v[e*4+j] - mean) * rs * g[c] + bb[c]);
    }
    dst[e * 64 + lane] = o;
  }
}

// LN2: in bf16 (short4), out fp32 (float4)
__launch_bounds__(256)
__global__ void ln2_kernel(const u16* __restrict__ xin, const float* __restrict__ g,
                           const float* __restrict__ bb, float* __restrict__ out)
{
  const int t = threadIdx.x, wv = t >> 6, lane = t & 63;
  const int tok = blockIdx.x * 4 + wv;
  const short4v* a0 = (const short4v*)(xin + (size_t)tok * CDIM);

  float v[12];
  float s1 = 0.f, s2 = 0.f;
#pragma unroll
  for (int e = 0; e < 3; e++) {
    short4v a = a0[e * 64 + lane];
#pragma unroll
    for (int j = 0; j < 4; j++) {
      float x = bf2f((u16)a[j]);
      v[e*4+j] = x; s1 += x; s2 += x * x;
    }
  }
#pragma unroll
  for (int m = 1; m < 64; m <<= 1) {
    s1 += __shfl_xor(s1, m);
    s2 += __shfl_xor(s2, m);
  }
  float mean = s1 * (1.f / 768.f);
  float var  = s2 * (1.f / 768.f) - mean * mean;
  float rs   = rsqrtf(var + 1e-5f);
  float4* dst = (float4*)(out + (size_t)tok * CDIM);
#pragma unroll
  for (int e = 0; e < 3; e++) {
    float4 o;
    int c = (e * 64 + lane) * 4;
    o.x = (v[e*4+0] - mean) * rs * g[c+0] + bb[c+0];
    o.y = (v[e*4+1] - mean) * rs * g[c+1] + bb[c+1];
    o.z = (v[e*4+2] - mean) * rs * g[c+2] + bb[c+2];
    o.w = (v[e*4+3] - mean) * rs * g[c+3] + bb[c+3];
    dst[e * 64 + lane] = o;
  }
}

static inline void launch_gemm(const u16* A, const u16* Wt, const float* bias,
                               const u16* res, void* C, int M, int N, int K,
                               int outbf, int relu, int resf, hipStream_t s)
{
  int gridx = N / 128, nwg = gridx * (M / 128);
  if (outbf) {
    if (relu)      gemm128<1,1,0><<<nwg, 512, 0, s>>>(A, Wt, bias, res, C, M, N, K, gridx, nwg);
    else if (resf) gemm128<1,0,1><<<nwg, 512, 0, s>>>(A, Wt, bias, res, C, M, N, K, gridx, nwg);
    else           gemm128<1,0,0><<<nwg, 512, 0, s>>>(A, Wt, bias, res, C, M, N, K, gridx, nwg);
  } else {
    gemm128<0,0,0><<<nwg, 512, 0, s>>>(A, Wt, bias, res, C, M, N, K, gridx, nwg);
  }
}

extern "C" void kernel_launch(void* const* d_in, const int* in_sizes, int n_in,
                              void* d_out, int out_size, void* d_ws, size_t ws_size,
                              hipStream_t stream)
{
  const float* x      = (const float*)d_in[0];
  const float* mask   = (const float*)d_in[1];
  const float* w_qkv  = (const float*)d_in[2];
  const float* b_qkv  = (const float*)d_in[3];
  const float* w_proj = (const float*)d_in[4];
  const float* b_proj = (const float*)d_in[5];
  const float* g1     = (const float*)d_in[6];
  const float* b1     = (const float*)d_in[7];
  const float* g2     = (const float*)d_in[8];
  const float* b2     = (const float*)d_in[9];
  const float* w_fc1  = (const float*)d_in[10];
  const float* b_fc1  = (const float*)d_in[11];
  const float* w_fc2  = (const float*)d_in[12];
  const float* b_fc2  = (const float*)d_in[13];
  float* out = (float*)d_out;

  // ws layout, total 297,271,296 B:
  //  A0 [0, 56.6M):        xg -> h[0:56.6M)
  //  A1 [56.6M, 226.5M):   QKV -> proj-out -> h[56.6M:226.5M)
  //  A2 [226.5M, 283.1M):  AO -> x1 -> y (in-place)
  //  W  [283.1M, 297.3M):  bf16 weights (contiguous: qkv|proj|fc1|fc2)
  char* base = (char*)d_ws;
  u16* A0 = (u16*)base;
  u16* A1 = (u16*)(base + 56623104);
  u16* A2 = (u16*)(base + 226492416);
  u16* Hb = (u16*)base;
  u16* wqkvb  = (u16*)(base + 283115520);
  u16* wprojb = wqkvb  + 1769472;
  u16* wfc1b  = wprojb + 589824;
  u16* wfc2b  = wfc1b  + 2359296;

  // all 4 weight conversions in ONE dispatch (outputs contiguous at wqkvb)
  conv4_bf16<<<1769472 / 256, 256, 0, stream>>>(w_qkv, w_proj, w_fc1, w_fc2, wqkvb);
  gather_x_bf16<<<NTOK / 4, 256, 0, stream>>>(x, A0);

  // QKV (full) then attention (all 576 windows) -> AO in A2
  launch_gemm(A0, wqkvb, b_qkv, nullptr, A1, NTOK, QKVDIM, CDIM, 1, 0, 0, stream);
  attn_mfma<<<576 * 12 / 4, 256, 0, stream>>>(A1, mask, A2);

  // proj: AO(A2) -> proj-out (A1, QKV dead)
  launch_gemm(A2, wprojb, b_proj, nullptr, A1, NTOK, CDIM, CDIM, 1, 0, 0, stream);

  // LN1: xg(A0) + proj-out(A1), both at row r -> x1 into A2 (AO dead)
  ln1_kernel<<<NTOK / 4, 256, 0, stream>>>(A0, A1, g1, b1, A2);

  // MLP, single dispatches: h full into A0+A1 (xg/proj dead); y in-place over x1
  launch_gemm(A2, wfc1b, b_fc1, nullptr, Hb, NTOK, HIDDIM, CDIM, 1, 1, 0, stream);
  launch_gemm(Hb, wfc2b, b_fc2, A2, A2, NTOK, CDIM, HIDDIM, 1, 0, 1, stream);

  // LN2 -> out (fp32)
  ln2_kernel<<<NTOK / 4, 256, 0, stream>>>(A2, g2, b2, out);
}